// Round 5
// baseline (452.160 us; speedup 1.0000x reference)
//
#include <hip/hip_runtime.h>

typedef __attribute__((ext_vector_type(8))) short short8;
typedef __attribute__((ext_vector_type(4))) float f32x4;

#define BN 256
#define HD 128

__device__ __forceinline__ unsigned short f2bf(float f) {
    union { float f; unsigned int i; } v; v.f = f;
    unsigned int lsb = (v.i >> 16) & 1u;
    v.i += 0x7fffu + lsb;
    return (unsigned short)(v.i >> 16);
}
__device__ __forceinline__ float fsigmoid(float x) {
    return __builtin_amdgcn_rcpf(1.0f + __expf(-x));
}
__device__ __forceinline__ float fsilu(float x) {
    return x * fsigmoid(x);
}

// ---------------------------------------------------------------------------
// prep_w: transpose + bf16-convert edg2_w / cor2_w (128x128 f32) into ws.
// Wt[n][k] = bf16(W[k][n])
// ---------------------------------------------------------------------------
__global__ __launch_bounds__(256) void prep_w(const float* __restrict__ e2w,
                                              const float* __restrict__ c2w,
                                              unsigned short* __restrict__ WtE,
                                              unsigned short* __restrict__ WtC) {
    int n = blockIdx.x;          // 0..127 output row
    int t = threadIdx.x;         // 0..255
    if (t < 128) WtE[n * 128 + t] = f2bf(e2w[t * 128 + n]);
    else         WtC[n * 128 + (t - 128)] = f2bf(c2w[(t - 128) * 128 + n]);
}

// ---------------------------------------------------------------------------
// prep_A: 512 blocks x 256 threads; block handles 4 rows; grp 0 -> edge
// weights, grp 1 -> coord weights.
// ---------------------------------------------------------------------------
__global__ __launch_bounds__(256) void prep_A(const float* __restrict__ h,
                                              const float* __restrict__ e1w,
                                              const float* __restrict__ e1b,
                                              const float* __restrict__ c1w,
                                              const float* __restrict__ c1b,
                                              float* __restrict__ A1e, float* __restrict__ A2e,
                                              float* __restrict__ A1c, float* __restrict__ A2c) {
    int r0 = blockIdx.x * 4;
    int k   = threadIdx.x & 127;
    int grp = threadIdx.x >> 7;            // 0: edge, 1: coord
    __shared__ float hsl[4][HD];
    {
        int rr = threadIdx.x >> 7;         // 0..1
        hsl[rr][k]     = h[(r0 + rr) * HD + k];
        hsl[rr + 2][k] = h[(r0 + rr + 2) * HD + k];
    }
    __syncthreads();
    const float* W = grp ? c1w : e1w;
    float s1[4] = {0,0,0,0}, s2[4] = {0,0,0,0};
#pragma unroll 4
    for (int f = 0; f < HD; ++f) {
        float w1 = W[f * HD + k];
        float w2 = W[(HD + f) * HD + k];
#pragma unroll
        for (int r = 0; r < 4; ++r) {
            float hv = hsl[r][f];
            s1[r] += hv * w1; s2[r] += hv * w2;
        }
    }
    float bb = grp ? c1b[k] : e1b[k];
    float* O1 = grp ? A1c : A1e;
    float* O2 = grp ? A2c : A2e;
#pragma unroll
    for (int r = 0; r < 4; ++r) {
        O1[(r0 + r) * HD + k] = s1[r] + bb;
        O2[(r0 + r) * HD + k] = s2[r];
    }
}

// ---------------------------------------------------------------------------
// Main fused kernel: one workgroup (1024 thr, 16 waves) per (b,i).
// 16 rows per wave -> acc is only 32 VGPRs; no spills under the 128 cap.
// ---------------------------------------------------------------------------
__global__ __launch_bounds__(1024, 4) void egc_main(
    const float* __restrict__ x, const float* __restrict__ h,
    const float* __restrict__ x0, const float* __restrict__ pmask,
    const float* __restrict__ e1w,
    const float* __restrict__ e2b, const float* __restrict__ eiw,
    const float* __restrict__ eib,
    const float* __restrict__ n1w, const float* __restrict__ n1b,
    const float* __restrict__ n2w, const float* __restrict__ n2b,
    const float* __restrict__ c1w, const float* __restrict__ c2b,
    const float* __restrict__ c3w, const float* __restrict__ c3b,
    const float* __restrict__ A1e, const float* __restrict__ A2e,
    const float* __restrict__ A1c, const float* __restrict__ A2c,
    const unsigned short* __restrict__ WtE, const unsigned short* __restrict__ WtC,
    float* __restrict__ xout, float* __restrict__ hout) {

    __shared__ __align__(16) float xs[BN][4];
    __shared__ __align__(16) float x0s[BN][4];
    __shared__ __align__(16) float d2s[BN], d02s[BN], rsh[BN];
    __shared__ __align__(16) float vE0[HD], vE1[HD], vE2[HD];
    __shared__ __align__(16) float vC0[HD], vC1[HD], vC2[HD];
    __shared__ __align__(16) float hsv[HD];
    __shared__ __align__(16) float aggbuf[16][HD];   // also reused by node MLP
    __shared__ __align__(16) float aggv[HD];
    __shared__ float updbuf[16][4];
    __shared__ float smask;

    const int tid = threadIdx.x;
    const int bi  = blockIdx.x;         // 0..2047
    const int b   = bi >> 8;
    const int i   = bi & 255;
    const int row = bi;

    // ---- setup loads ----
    if (tid < BN) {
        int gj = b * BN + tid;
        xs[tid][0]  = x[gj * 3 + 0];
        xs[tid][1]  = x[gj * 3 + 1];
        xs[tid][2]  = x[gj * 3 + 2];
        x0s[tid][0] = x0[gj * 3 + 0];
        x0s[tid][1] = x0[gj * 3 + 1];
        x0s[tid][2] = x0[gj * 3 + 2];
    } else if (tid < BN + HD) {
        int t = tid - BN;
        vE0[t] = A1e[row * HD + t];
        vE1[t] = e1w[256 * HD + t];
        vE2[t] = e1w[257 * HD + t];
    } else if (tid < BN + 2 * HD) {
        int t = tid - BN - HD;
        vC0[t] = A1c[row * HD + t];
        vC1[t] = c1w[256 * HD + t];
        vC2[t] = c1w[257 * HD + t];
    } else if (tid < BN + 3 * HD) {
        int t = tid - BN - 2 * HD;
        hsv[t] = h[row * HD + t];
    }
    if (tid == 1023) smask = pmask[row];
    __syncthreads();

    // ---- pairwise distances vs row i ----
    if (tid < BN) {
        float dx = xs[i][0] - xs[tid][0];
        float dy = xs[i][1] - xs[tid][1];
        float dz = xs[i][2] - xs[tid][2];
        float d2 = dx * dx + dy * dy + dz * dz;
        d2s[tid] = d2;
        float dist = (d2 > 0.0f) ? sqrtf(d2) : 0.0f;
        rsh[tid] = __builtin_amdgcn_rcpf(dist + 1.0f);
        float ex = x0s[i][0] - x0s[tid][0];
        float ey = x0s[i][1] - x0s[tid][1];
        float ez = x0s[i][2] - x0s[tid][2];
        d02s[tid] = ex * ex + ey * ey + ez * ez;
    }
    __syncthreads();

    const int lane = tid & 63, wv = tid >> 6;   // 16 waves
    const int c = lane & 15, q = lane >> 4;
    const int ra = wv * 16 + c;                 // A-fragment row

    // =================== EDGE PATH ===================
    {
        const float* A2g = A2e + (size_t)b * BN * HD;
        f32x4 acc[8];
        const f32x4 zf = {0.f, 0.f, 0.f, 0.f};
#pragma unroll
        for (int nt = 0; nt < 8; ++nt) acc[nt] = zf;
        const float d2v = d2s[ra], d02v = d02s[ra];
#pragma unroll
        for (int ks = 0; ks < 4; ++ks) {
            const int kb = ks * 32 + q * 8;
            float4 alo = *(const float4*)(A2g + ra * HD + kb);
            float4 ahi = *(const float4*)(A2g + ra * HD + kb + 4);
            float4 p0 = *(const float4*)(vE0 + kb);
            float4 p0h = *(const float4*)(vE0 + kb + 4);
            float4 p1 = *(const float4*)(vE1 + kb);
            float4 p1h = *(const float4*)(vE1 + kb + 4);
            float4 p2 = *(const float4*)(vE2 + kb);
            float4 p2h = *(const float4*)(vE2 + kb + 4);
            short8 af;
            af[0] = (short)f2bf(fsilu(alo.x + p0.x + d2v * p1.x + d02v * p2.x));
            af[1] = (short)f2bf(fsilu(alo.y + p0.y + d2v * p1.y + d02v * p2.y));
            af[2] = (short)f2bf(fsilu(alo.z + p0.z + d2v * p1.z + d02v * p2.z));
            af[3] = (short)f2bf(fsilu(alo.w + p0.w + d2v * p1.w + d02v * p2.w));
            af[4] = (short)f2bf(fsilu(ahi.x + p0h.x + d2v * p1h.x + d02v * p2h.x));
            af[5] = (short)f2bf(fsilu(ahi.y + p0h.y + d2v * p1h.y + d02v * p2h.y));
            af[6] = (short)f2bf(fsilu(ahi.z + p0h.z + d2v * p1h.z + d02v * p2h.z));
            af[7] = (short)f2bf(fsilu(ahi.w + p0h.w + d2v * p1h.w + d02v * p2h.w));
#pragma unroll
            for (int nt = 0; nt < 8; ++nt) {
                short8 Bf = *(const short8*)(WtE + (nt * 16 + c) * HD + kb);
                acc[nt] = __builtin_amdgcn_mfma_f32_16x16x32_bf16(af, Bf, acc[nt], 0, 0, 0);
            }
        }
        // epilogue: gate + aggregate
        float b2l[8], wIl[8];
#pragma unroll
        for (int nt = 0; nt < 8; ++nt) {
            b2l[nt] = e2b[nt * 16 + c];
            wIl[nt] = eiw[nt * 16 + c];
        }
        float bI = eib[0];
        float aggp[8] = {0,0,0,0,0,0,0,0};
#pragma unroll
        for (int reg = 0; reg < 4; ++reg) {
            int r = wv * 16 + q * 4 + reg;
            float mv[8]; float ed = 0.f;
#pragma unroll
            for (int nt = 0; nt < 8; ++nt) {
                mv[nt] = fsilu(acc[nt][reg] + b2l[nt]);
                ed += mv[nt] * wIl[nt];
            }
            ed += __shfl_xor(ed, 1);
            ed += __shfl_xor(ed, 2);
            ed += __shfl_xor(ed, 4);
            ed += __shfl_xor(ed, 8);
            float e = (r == i) ? 0.0f : fsigmoid(ed + bI);
#pragma unroll
            for (int nt = 0; nt < 8; ++nt) aggp[nt] += e * mv[nt];
        }
#pragma unroll
        for (int nt = 0; nt < 8; ++nt) {
            aggp[nt] += __shfl_xor(aggp[nt], 16);
            aggp[nt] += __shfl_xor(aggp[nt], 32);
        }
        if (q == 0)
#pragma unroll
            for (int nt = 0; nt < 8; ++nt) aggbuf[wv][nt * 16 + c] = aggp[nt];
    }
    __syncthreads();
    if (tid < HD) {
        float s = 0.f;
#pragma unroll
        for (int w = 0; w < 16; ++w) s += aggbuf[w][tid];
        aggv[tid] = s * (1.0f / 256.0f);
    }
    __syncthreads();

    // =================== COORD PATH ===================
    {
        const float* A2g = A2c + (size_t)b * BN * HD;
        f32x4 acc[8];
        const f32x4 zf = {0.f, 0.f, 0.f, 0.f};
#pragma unroll
        for (int nt = 0; nt < 8; ++nt) acc[nt] = zf;
        const float d2v = d2s[ra], d02v = d02s[ra];
#pragma unroll
        for (int ks = 0; ks < 4; ++ks) {
            const int kb = ks * 32 + q * 8;
            float4 alo = *(const float4*)(A2g + ra * HD + kb);
            float4 ahi = *(const float4*)(A2g + ra * HD + kb + 4);
            float4 p0 = *(const float4*)(vC0 + kb);
            float4 p0h = *(const float4*)(vC0 + kb + 4);
            float4 p1 = *(const float4*)(vC1 + kb);
            float4 p1h = *(const float4*)(vC1 + kb + 4);
            float4 p2 = *(const float4*)(vC2 + kb);
            float4 p2h = *(const float4*)(vC2 + kb + 4);
            short8 af;
            af[0] = (short)f2bf(fsilu(alo.x + p0.x + d2v * p1.x + d02v * p2.x));
            af[1] = (short)f2bf(fsilu(alo.y + p0.y + d2v * p1.y + d02v * p2.y));
            af[2] = (short)f2bf(fsilu(alo.z + p0.z + d2v * p1.z + d02v * p2.z));
            af[3] = (short)f2bf(fsilu(alo.w + p0.w + d2v * p1.w + d02v * p2.w));
            af[4] = (short)f2bf(fsilu(ahi.x + p0h.x + d2v * p1h.x + d02v * p2h.x));
            af[5] = (short)f2bf(fsilu(ahi.y + p0h.y + d2v * p1h.y + d02v * p2h.y));
            af[6] = (short)f2bf(fsilu(ahi.z + p0h.z + d2v * p1h.z + d02v * p2h.z));
            af[7] = (short)f2bf(fsilu(ahi.w + p0h.w + d2v * p1h.w + d02v * p2h.w));
#pragma unroll
            for (int nt = 0; nt < 8; ++nt) {
                short8 Bf = *(const short8*)(WtC + (nt * 16 + c) * HD + kb);
                acc[nt] = __builtin_amdgcn_mfma_f32_16x16x32_bf16(af, Bf, acc[nt], 0, 0, 0);
            }
        }
        float b2l[8], w3l[8];
#pragma unroll
        for (int nt = 0; nt < 8; ++nt) {
            b2l[nt] = c2b[nt * 16 + c];
            w3l[nt] = c3w[nt * 16 + c];
        }
        float b3 = c3b[0];
        float updp = 0.f;
        float xic = (c < 3) ? xs[i][c] : 0.f;
#pragma unroll
        for (int reg = 0; reg < 4; ++reg) {
            int r = wv * 16 + q * 4 + reg;
            float cd = 0.f;
#pragma unroll
            for (int nt = 0; nt < 8; ++nt)
                cd += fsilu(acc[nt][reg] + b2l[nt]) * w3l[nt];
            cd += __shfl_xor(cd, 1);
            cd += __shfl_xor(cd, 2);
            cd += __shfl_xor(cd, 4);
            cd += __shfl_xor(cd, 8);
            float cw = cd + b3;
            if (c < 3 && r != i)
                updp += cw * (xic - xs[r][c]) * rsh[r];
        }
        updp += __shfl_xor(updp, 16);
        updp += __shfl_xor(updp, 32);
        if (q == 0 && c < 3) updbuf[wv][c] = updp;
    }
    __syncthreads();

    // x output (float32)
    if (tid < 3) {
        float u = 0.f;
#pragma unroll
        for (int w = 0; w < 16; ++w) u += updbuf[w][tid];
        u *= (1.0f / 256.0f);
        xout[row * 3 + tid] = (xs[i][tid] + u) * smask;
    }

    // =================== NODE MLP ===================
    // h_next = (h + silu([h,agg]@W1 + b1)@W2 + b2) * mask
    float* npart = &aggbuf[0][0];           // rows 0..7
    float* qv    = &aggbuf[8][0];           // row 8
    {
        int k = tid & 127, part = tid >> 7;        // 0..7, 32 features each
        const float* src = (part < 4) ? hsv : aggv;
        int fbase = (part & 3) * 32;
        int wrow = ((part < 4) ? 0 : HD) + fbase;
        float s = 0.f;
#pragma unroll 4
        for (int f = 0; f < 32; ++f)
            s += src[fbase + f] * n1w[(size_t)(wrow + f) * HD + k];
        npart[part * HD + k] = s;
    }
    __syncthreads();
    if (tid < HD) {
        float s = n1b[tid];
#pragma unroll
        for (int p = 0; p < 8; ++p) s += npart[p * HD + tid];
        qv[tid] = fsilu(s);
    }
    __syncthreads();
    {
        int o = tid & 127, p = tid >> 7;           // 16 features each
        float s = 0.f;
#pragma unroll 4
        for (int f = 0; f < 16; ++f) {
            int ff = p * 16 + f;
            s += qv[ff] * n2w[(size_t)ff * HD + o];
        }
        npart[p * HD + o] = s;                      // overwrite rows 0..7 (consumed)
    }
    __syncthreads();
    if (tid < HD) {
        float s = 0.f;
#pragma unroll
        for (int p = 0; p < 8; ++p) s += npart[p * HD + tid];
        hout[(size_t)row * HD + tid] = (hsv[tid] + s + n2b[tid]) * smask;
    }
}

extern "C" void kernel_launch(void* const* d_in, const int* in_sizes, int n_in,
                              void* d_out, int out_size, void* d_ws, size_t ws_size,
                              hipStream_t stream) {
    const float* x    = (const float*)d_in[0];
    const float* h    = (const float*)d_in[1];
    const float* x0   = (const float*)d_in[2];
    const float* pm   = (const float*)d_in[3];
    const float* e1w  = (const float*)d_in[4];
    const float* e1b  = (const float*)d_in[5];
    const float* e2w  = (const float*)d_in[6];
    const float* e2b  = (const float*)d_in[7];
    const float* eiw  = (const float*)d_in[8];
    const float* eib  = (const float*)d_in[9];
    const float* n1w  = (const float*)d_in[10];
    const float* n1b  = (const float*)d_in[11];
    const float* n2w  = (const float*)d_in[12];
    const float* n2b  = (const float*)d_in[13];
    const float* c1w  = (const float*)d_in[14];
    const float* c1b  = (const float*)d_in[15];
    const float* c2w  = (const float*)d_in[16];
    const float* c2b  = (const float*)d_in[17];
    const float* c3w  = (const float*)d_in[18];
    const float* c3b  = (const float*)d_in[19];

    float* wsf = (float*)d_ws;
    const size_t nA = 2048 * 128;
    float* A1e = wsf;
    float* A2e = wsf + nA;
    float* A1c = wsf + 2 * nA;
    float* A2c = wsf + 3 * nA;
    unsigned short* WtE = (unsigned short*)(wsf + 4 * nA);
    unsigned short* WtC = WtE + 128 * 128;

    float* xout = (float*)d_out;
    float* hout = xout + 8 * 256 * 3;

    prep_w<<<dim3(128), dim3(256), 0, stream>>>(e2w, c2w, WtE, WtC);
    prep_A<<<dim3(512), dim3(256), 0, stream>>>(h, e1w, e1b, c1w, c1b, A1e, A2e, A1c, A2c);
    egc_main<<<dim3(2048), dim3(1024), 0, stream>>>(
        x, h, x0, pm, e1w, e2b, eiw, eib, n1w, n1b, n2w, n2b,
        c1w, c2b, c3w, c3b, A1e, A2e, A1c, A2c, WtE, WtC, xout, hout);
}

// Round 6
// 253.402 us; speedup vs baseline: 1.7844x; 1.7844x over previous
//
#include <hip/hip_runtime.h>

typedef __attribute__((ext_vector_type(8))) short short8;
typedef __attribute__((ext_vector_type(8))) unsigned short ushort8_t;
typedef __attribute__((ext_vector_type(4))) float f32x4;

#define BN 256
#define HD 128
#define WSTRIDE 136   // padded LDS row stride (bf16 elems): 2-way bank alias = free

__device__ __forceinline__ unsigned short f2bf(float f) {
    union { float f; unsigned int i; } v; v.f = f;
    unsigned int lsb = (v.i >> 16) & 1u;
    v.i += 0x7fffu + lsb;
    return (unsigned short)(v.i >> 16);
}
__device__ __forceinline__ float fsigmoid(float x) {
    return __builtin_amdgcn_rcpf(1.0f + __expf(-x));
}
__device__ __forceinline__ float fsilu(float x) {
    return x * fsigmoid(x);
}

// ---------------------------------------------------------------------------
// prep_w: transpose + bf16-convert edg2_w / cor2_w (128x128 f32) into ws.
// Wt[n][k] = bf16(W[k][n])
// ---------------------------------------------------------------------------
__global__ __launch_bounds__(256) void prep_w(const float* __restrict__ e2w,
                                              const float* __restrict__ c2w,
                                              unsigned short* __restrict__ WtE,
                                              unsigned short* __restrict__ WtC) {
    int n = blockIdx.x;          // 0..127 output row
    int t = threadIdx.x;         // 0..255
    if (t < 128) WtE[n * 128 + t] = f2bf(e2w[t * 128 + n]);
    else         WtC[n * 128 + (t - 128)] = f2bf(c2w[(t - 128) * 128 + n]);
}

// ---------------------------------------------------------------------------
// prep_A: 512 blocks x 256 threads; block handles 4 rows; grp 0 -> edge
// weights, grp 1 -> coord weights.
// ---------------------------------------------------------------------------
__global__ __launch_bounds__(256) void prep_A(const float* __restrict__ h,
                                              const float* __restrict__ e1w,
                                              const float* __restrict__ e1b,
                                              const float* __restrict__ c1w,
                                              const float* __restrict__ c1b,
                                              float* __restrict__ A1e, float* __restrict__ A2e,
                                              float* __restrict__ A1c, float* __restrict__ A2c) {
    int r0 = blockIdx.x * 4;
    int k   = threadIdx.x & 127;
    int grp = threadIdx.x >> 7;            // 0: edge, 1: coord
    __shared__ float hsl[4][HD];
    {
        int rr = threadIdx.x >> 7;         // 0..1
        hsl[rr][k]     = h[(r0 + rr) * HD + k];
        hsl[rr + 2][k] = h[(r0 + rr + 2) * HD + k];
    }
    __syncthreads();
    const float* W = grp ? c1w : e1w;
    float s1[4] = {0,0,0,0}, s2[4] = {0,0,0,0};
#pragma unroll 4
    for (int f = 0; f < HD; ++f) {
        float w1 = W[f * HD + k];
        float w2 = W[(HD + f) * HD + k];
#pragma unroll
        for (int r = 0; r < 4; ++r) {
            float hv = hsl[r][f];
            s1[r] += hv * w1; s2[r] += hv * w2;
        }
    }
    float bb = grp ? c1b[k] : e1b[k];
    float* O1 = grp ? A1c : A1e;
    float* O2 = grp ? A2c : A2e;
#pragma unroll
    for (int r = 0; r < 4; ++r) {
        O1[(r0 + r) * HD + k] = s1[r] + bb;
        O2[(r0 + r) * HD + k] = s2[r];
    }
}

// ---------------------------------------------------------------------------
// Main fused kernel: one workgroup (1024 thr, 16 waves) per (b,i).
// B-operand weights staged in LDS (padded stride) -> no per-MFMA L2 traffic.
// ---------------------------------------------------------------------------
__global__ __launch_bounds__(1024, 4) void egc_main(
    const float* __restrict__ x, const float* __restrict__ h,
    const float* __restrict__ x0, const float* __restrict__ pmask,
    const float* __restrict__ e1w,
    const float* __restrict__ e2b, const float* __restrict__ eiw,
    const float* __restrict__ eib,
    const float* __restrict__ n1w, const float* __restrict__ n1b,
    const float* __restrict__ n2w, const float* __restrict__ n2b,
    const float* __restrict__ c1w, const float* __restrict__ c2b,
    const float* __restrict__ c3w, const float* __restrict__ c3b,
    const float* __restrict__ A1e, const float* __restrict__ A2e,
    const float* __restrict__ A1c, const float* __restrict__ A2c,
    const unsigned short* __restrict__ WtE, const unsigned short* __restrict__ WtC,
    float* __restrict__ xout, float* __restrict__ hout) {

    __shared__ __align__(16) unsigned short WtEl[HD * WSTRIDE];  // 34.8 KB
    __shared__ __align__(16) unsigned short WtCl[HD * WSTRIDE];  // 34.8 KB
    __shared__ __align__(16) float xs[BN][4];
    __shared__ __align__(16) float x0s[BN][4];
    __shared__ __align__(16) float d2s[BN], d02s[BN], rsh[BN];
    __shared__ __align__(16) float vE0[HD], vE1[HD], vE2[HD];
    __shared__ __align__(16) float vC0[HD], vC1[HD], vC2[HD];
    __shared__ __align__(16) float hsv[HD];
    __shared__ __align__(16) float aggbuf[16][HD];   // also reused by node MLP
    __shared__ __align__(16) float aggv[HD];
    __shared__ float updbuf[16][4];
    __shared__ float smask;

    const int tid = threadIdx.x;
    const int bi  = blockIdx.x;         // 0..2047
    const int b   = bi >> 8;
    const int i   = bi & 255;
    const int row = bi;

    // ---- stage weights into LDS (padded rows) ----
#pragma unroll
    for (int u = 0; u < 2; ++u) {
        int idx = u * 1024 + tid;        // 0..2047 chunks of 8 bf16
        int n   = idx >> 4;              // row 0..127
        int k8  = (idx & 15) * 8;
        *(ushort8_t*)(WtEl + n * WSTRIDE + k8) = *(const ushort8_t*)(WtE + n * HD + k8);
        *(ushort8_t*)(WtCl + n * WSTRIDE + k8) = *(const ushort8_t*)(WtC + n * HD + k8);
    }

    // ---- setup loads ----
    if (tid < BN) {
        int gj = b * BN + tid;
        xs[tid][0]  = x[gj * 3 + 0];
        xs[tid][1]  = x[gj * 3 + 1];
        xs[tid][2]  = x[gj * 3 + 2];
        x0s[tid][0] = x0[gj * 3 + 0];
        x0s[tid][1] = x0[gj * 3 + 1];
        x0s[tid][2] = x0[gj * 3 + 2];
    } else if (tid < BN + HD) {
        int t = tid - BN;
        vE0[t] = A1e[row * HD + t];
        vE1[t] = e1w[256 * HD + t];
        vE2[t] = e1w[257 * HD + t];
    } else if (tid < BN + 2 * HD) {
        int t = tid - BN - HD;
        vC0[t] = A1c[row * HD + t];
        vC1[t] = c1w[256 * HD + t];
        vC2[t] = c1w[257 * HD + t];
    } else if (tid < BN + 3 * HD) {
        int t = tid - BN - 2 * HD;
        hsv[t] = h[row * HD + t];
    }
    if (tid == 1023) smask = pmask[row];
    __syncthreads();

    // ---- pairwise distances vs row i ----
    if (tid < BN) {
        float dx = xs[i][0] - xs[tid][0];
        float dy = xs[i][1] - xs[tid][1];
        float dz = xs[i][2] - xs[tid][2];
        float d2 = dx * dx + dy * dy + dz * dz;
        d2s[tid] = d2;
        float dist = (d2 > 0.0f) ? sqrtf(d2) : 0.0f;
        rsh[tid] = __builtin_amdgcn_rcpf(dist + 1.0f);
        float ex = x0s[i][0] - x0s[tid][0];
        float ey = x0s[i][1] - x0s[tid][1];
        float ez = x0s[i][2] - x0s[tid][2];
        d02s[tid] = ex * ex + ey * ey + ez * ez;
    }
    __syncthreads();

    const int lane = tid & 63, wv = tid >> 6;   // 16 waves
    const int c = lane & 15, q = lane >> 4;
    const int ra = wv * 16 + c;                 // A-fragment row

    // =================== EDGE PATH ===================
    {
        const float* A2g = A2e + (size_t)b * BN * HD;
        f32x4 acc[8];
        const f32x4 zf = {0.f, 0.f, 0.f, 0.f};
#pragma unroll
        for (int nt = 0; nt < 8; ++nt) acc[nt] = zf;
        const float d2v = d2s[ra], d02v = d02s[ra];
#pragma unroll
        for (int ks = 0; ks < 4; ++ks) {
            const int kb = ks * 32 + q * 8;
            float4 alo = *(const float4*)(A2g + ra * HD + kb);
            float4 ahi = *(const float4*)(A2g + ra * HD + kb + 4);
            float4 p0 = *(const float4*)(vE0 + kb);
            float4 p0h = *(const float4*)(vE0 + kb + 4);
            float4 p1 = *(const float4*)(vE1 + kb);
            float4 p1h = *(const float4*)(vE1 + kb + 4);
            float4 p2 = *(const float4*)(vE2 + kb);
            float4 p2h = *(const float4*)(vE2 + kb + 4);
            short8 af;
            af[0] = (short)f2bf(fsilu(alo.x + p0.x + d2v * p1.x + d02v * p2.x));
            af[1] = (short)f2bf(fsilu(alo.y + p0.y + d2v * p1.y + d02v * p2.y));
            af[2] = (short)f2bf(fsilu(alo.z + p0.z + d2v * p1.z + d02v * p2.z));
            af[3] = (short)f2bf(fsilu(alo.w + p0.w + d2v * p1.w + d02v * p2.w));
            af[4] = (short)f2bf(fsilu(ahi.x + p0h.x + d2v * p1h.x + d02v * p2h.x));
            af[5] = (short)f2bf(fsilu(ahi.y + p0h.y + d2v * p1h.y + d02v * p2h.y));
            af[6] = (short)f2bf(fsilu(ahi.z + p0h.z + d2v * p1h.z + d02v * p2h.z));
            af[7] = (short)f2bf(fsilu(ahi.w + p0h.w + d2v * p1h.w + d02v * p2h.w));
#pragma unroll
            for (int nt = 0; nt < 8; ++nt) {
                short8 Bf = *(const short8*)(WtEl + (nt * 16 + c) * WSTRIDE + kb);
                acc[nt] = __builtin_amdgcn_mfma_f32_16x16x32_bf16(af, Bf, acc[nt], 0, 0, 0);
            }
        }
        // epilogue: gate + aggregate
        float b2l[8], wIl[8];
#pragma unroll
        for (int nt = 0; nt < 8; ++nt) {
            b2l[nt] = e2b[nt * 16 + c];
            wIl[nt] = eiw[nt * 16 + c];
        }
        float bI = eib[0];
        float aggp[8] = {0,0,0,0,0,0,0,0};
#pragma unroll
        for (int reg = 0; reg < 4; ++reg) {
            int r = wv * 16 + q * 4 + reg;
            float mv[8]; float ed = 0.f;
#pragma unroll
            for (int nt = 0; nt < 8; ++nt) {
                mv[nt] = fsilu(acc[nt][reg] + b2l[nt]);
                ed += mv[nt] * wIl[nt];
            }
            ed += __shfl_xor(ed, 1);
            ed += __shfl_xor(ed, 2);
            ed += __shfl_xor(ed, 4);
            ed += __shfl_xor(ed, 8);
            float e = (r == i) ? 0.0f : fsigmoid(ed + bI);
#pragma unroll
            for (int nt = 0; nt < 8; ++nt) aggp[nt] += e * mv[nt];
        }
#pragma unroll
        for (int nt = 0; nt < 8; ++nt) {
            aggp[nt] += __shfl_xor(aggp[nt], 16);
            aggp[nt] += __shfl_xor(aggp[nt], 32);
        }
        if (q == 0)
#pragma unroll
            for (int nt = 0; nt < 8; ++nt) aggbuf[wv][nt * 16 + c] = aggp[nt];
    }
    __syncthreads();
    if (tid < HD) {
        float s = 0.f;
#pragma unroll
        for (int w = 0; w < 16; ++w) s += aggbuf[w][tid];
        aggv[tid] = s * (1.0f / 256.0f);
    }
    __syncthreads();

    // =================== COORD PATH ===================
    {
        const float* A2g = A2c + (size_t)b * BN * HD;
        f32x4 acc[8];
        const f32x4 zf = {0.f, 0.f, 0.f, 0.f};
#pragma unroll
        for (int nt = 0; nt < 8; ++nt) acc[nt] = zf;
        const float d2v = d2s[ra], d02v = d02s[ra];
#pragma unroll
        for (int ks = 0; ks < 4; ++ks) {
            const int kb = ks * 32 + q * 8;
            float4 alo = *(const float4*)(A2g + ra * HD + kb);
            float4 ahi = *(const float4*)(A2g + ra * HD + kb + 4);
            float4 p0 = *(const float4*)(vC0 + kb);
            float4 p0h = *(const float4*)(vC0 + kb + 4);
            float4 p1 = *(const float4*)(vC1 + kb);
            float4 p1h = *(const float4*)(vC1 + kb + 4);
            float4 p2 = *(const float4*)(vC2 + kb);
            float4 p2h = *(const float4*)(vC2 + kb + 4);
            short8 af;
            af[0] = (short)f2bf(fsilu(alo.x + p0.x + d2v * p1.x + d02v * p2.x));
            af[1] = (short)f2bf(fsilu(alo.y + p0.y + d2v * p1.y + d02v * p2.y));
            af[2] = (short)f2bf(fsilu(alo.z + p0.z + d2v * p1.z + d02v * p2.z));
            af[3] = (short)f2bf(fsilu(alo.w + p0.w + d2v * p1.w + d02v * p2.w));
            af[4] = (short)f2bf(fsilu(ahi.x + p0h.x + d2v * p1h.x + d02v * p2h.x));
            af[5] = (short)f2bf(fsilu(ahi.y + p0h.y + d2v * p1h.y + d02v * p2h.y));
            af[6] = (short)f2bf(fsilu(ahi.z + p0h.z + d2v * p1h.z + d02v * p2h.z));
            af[7] = (short)f2bf(fsilu(ahi.w + p0h.w + d2v * p1h.w + d02v * p2h.w));
#pragma unroll
            for (int nt = 0; nt < 8; ++nt) {
                short8 Bf = *(const short8*)(WtCl + (nt * 16 + c) * WSTRIDE + kb);
                acc[nt] = __builtin_amdgcn_mfma_f32_16x16x32_bf16(af, Bf, acc[nt], 0, 0, 0);
            }
        }
        float b2l[8], w3l[8];
#pragma unroll
        for (int nt = 0; nt < 8; ++nt) {
            b2l[nt] = c2b[nt * 16 + c];
            w3l[nt] = c3w[nt * 16 + c];
        }
        float b3 = c3b[0];
        float updp = 0.f;
        float xic = (c < 3) ? xs[i][c] : 0.f;
#pragma unroll
        for (int reg = 0; reg < 4; ++reg) {
            int r = wv * 16 + q * 4 + reg;
            float cd = 0.f;
#pragma unroll
            for (int nt = 0; nt < 8; ++nt)
                cd += fsilu(acc[nt][reg] + b2l[nt]) * w3l[nt];
            cd += __shfl_xor(cd, 1);
            cd += __shfl_xor(cd, 2);
            cd += __shfl_xor(cd, 4);
            cd += __shfl_xor(cd, 8);
            float cw = cd + b3;
            if (c < 3 && r != i)
                updp += cw * (xic - xs[r][c]) * rsh[r];
        }
        updp += __shfl_xor(updp, 16);
        updp += __shfl_xor(updp, 32);
        if (q == 0 && c < 3) updbuf[wv][c] = updp;
    }
    __syncthreads();

    // x output (float32)
    if (tid < 3) {
        float u = 0.f;
#pragma unroll
        for (int w = 0; w < 16; ++w) u += updbuf[w][tid];
        u *= (1.0f / 256.0f);
        xout[row * 3 + tid] = (xs[i][tid] + u) * smask;
    }

    // =================== NODE MLP ===================
    // h_next = (h + silu([h,agg]@W1 + b1)@W2 + b2) * mask
    float* npart = &aggbuf[0][0];           // rows 0..7
    float* qv    = &aggbuf[8][0];           // row 8
    {
        int k = tid & 127, part = tid >> 7;        // 0..7, 32 features each
        const float* src = (part < 4) ? hsv : aggv;
        int fbase = (part & 3) * 32;
        int wrow = ((part < 4) ? 0 : HD) + fbase;
        float s = 0.f;
#pragma unroll 4
        for (int f = 0; f < 32; ++f)
            s += src[fbase + f] * n1w[(size_t)(wrow + f) * HD + k];
        npart[part * HD + k] = s;
    }
    __syncthreads();
    if (tid < HD) {
        float s = n1b[tid];
#pragma unroll
        for (int p = 0; p < 8; ++p) s += npart[p * HD + tid];
        qv[tid] = fsilu(s);
    }
    __syncthreads();
    {
        int o = tid & 127, p = tid >> 7;           // 16 features each
        float s = 0.f;
#pragma unroll 4
        for (int f = 0; f < 16; ++f) {
            int ff = p * 16 + f;
            s += qv[ff] * n2w[(size_t)ff * HD + o];
        }
        npart[p * HD + o] = s;                      // overwrite rows 0..7 (consumed)
    }
    __syncthreads();
    if (tid < HD) {
        float s = 0.f;
#pragma unroll
        for (int p = 0; p < 8; ++p) s += npart[p * HD + tid];
        hout[(size_t)row * HD + tid] = (hsv[tid] + s + n2b[tid]) * smask;
    }
}

extern "C" void kernel_launch(void* const* d_in, const int* in_sizes, int n_in,
                              void* d_out, int out_size, void* d_ws, size_t ws_size,
                              hipStream_t stream) {
    const float* x    = (const float*)d_in[0];
    const float* h    = (const float*)d_in[1];
    const float* x0   = (const float*)d_in[2];
    const float* pm   = (const float*)d_in[3];
    const float* e1w  = (const float*)d_in[4];
    const float* e1b  = (const float*)d_in[5];
    const float* e2w  = (const float*)d_in[6];
    const float* e2b  = (const float*)d_in[7];
    const float* eiw  = (const float*)d_in[8];
    const float* eib  = (const float*)d_in[9];
    const float* n1w  = (const float*)d_in[10];
    const float* n1b  = (const float*)d_in[11];
    const float* n2w  = (const float*)d_in[12];
    const float* n2b  = (const float*)d_in[13];
    const float* c1w  = (const float*)d_in[14];
    const float* c1b  = (const float*)d_in[15];
    const float* c2w  = (const float*)d_in[16];
    const float* c2b  = (const float*)d_in[17];
    const float* c3w  = (const float*)d_in[18];
    const float* c3b  = (const float*)d_in[19];

    float* wsf = (float*)d_ws;
    const size_t nA = 2048 * 128;
    float* A1e = wsf;
    float* A2e = wsf + nA;
    float* A1c = wsf + 2 * nA;
    float* A2c = wsf + 3 * nA;
    unsigned short* WtE = (unsigned short*)(wsf + 4 * nA);
    unsigned short* WtC = WtE + 128 * 128;

    float* xout = (float*)d_out;
    float* hout = xout + 8 * 256 * 3;

    prep_w<<<dim3(128), dim3(256), 0, stream>>>(e2w, c2w, WtE, WtC);
    prep_A<<<dim3(512), dim3(256), 0, stream>>>(h, e1w, e1b, c1w, c1b, A1e, A2e, A1c, A2c);
    egc_main<<<dim3(2048), dim3(1024), 0, stream>>>(
        x, h, x0, pm, e1w, e2b, eiw, eib, n1w, n1b, n2w, n2b,
        c1w, c2b, c3w, c3b, A1e, A2e, A1c, A2c, WtE, WtC, xout, hout);
}

// Round 7
// 221.887 us; speedup vs baseline: 2.0378x; 1.1420x over previous
//
#include <hip/hip_runtime.h>

typedef __attribute__((ext_vector_type(8))) short short8;
typedef __attribute__((ext_vector_type(8))) unsigned short ushort8_t;
typedef __attribute__((ext_vector_type(4))) float f32x4;

#define BN 256
#define HD 128
#define WSTRIDE 136   // padded LDS row stride (bf16 elems): 2-way bank alias = free

__device__ __forceinline__ unsigned short f2bf(float f) {
    union { float f; unsigned int i; } v; v.f = f;
    unsigned int lsb = (v.i >> 16) & 1u;
    v.i += 0x7fffu + lsb;
    return (unsigned short)(v.i >> 16);
}
__device__ __forceinline__ float fsigmoid(float x) {
    return __builtin_amdgcn_rcpf(1.0f + __expf(-x));
}
__device__ __forceinline__ float fsilu(float x) {
    return x * fsigmoid(x);
}

// ---------------------------------------------------------------------------
// prep_tw: transpose + bf16-convert six 128x128 weight blocks into ws.
//   WtE/WtC   : edg2_w / cor2_w transposed       Wt[n][k] = W[k][n]
//   W1e1/W1e2 : edg1_w rows 0-127 / 128-255 transposed
//   W1c1/W1c2 : cor1_w rows 0-127 / 128-255 transposed
// ---------------------------------------------------------------------------
__global__ __launch_bounds__(256) void prep_tw(const float* __restrict__ e2w,
                                               const float* __restrict__ c2w,
                                               const float* __restrict__ e1w,
                                               const float* __restrict__ c1w,
                                               unsigned short* __restrict__ WtE,
                                               unsigned short* __restrict__ WtC,
                                               unsigned short* __restrict__ W1e1,
                                               unsigned short* __restrict__ W1e2,
                                               unsigned short* __restrict__ W1c1,
                                               unsigned short* __restrict__ W1c2) {
    int k = blockIdx.x;          // 0..127 source row
    int t = threadIdx.x;         // 0..255
    int n = t & 127;
    if (t < 128) {
        WtE [n * 128 + k] = f2bf(e2w[k * 128 + n]);
        W1e1[n * 128 + k] = f2bf(e1w[k * 128 + n]);
        W1e2[n * 128 + k] = f2bf(e1w[(128 + k) * 128 + n]);
    } else {
        WtC [n * 128 + k] = f2bf(c2w[k * 128 + n]);
        W1c1[n * 128 + k] = f2bf(c1w[k * 128 + n]);
        W1c2[n * 128 + k] = f2bf(c1w[(128 + k) * 128 + n]);
    }
}

// ---------------------------------------------------------------------------
// prep_gemm: A1e/A2e/A1c/A2c = h @ W-block (+bias on A1*), via MFMA.
// 128 blocks x 256 thr (4 waves); block = 16 rows; wave -> one output matrix.
// ---------------------------------------------------------------------------
__global__ __launch_bounds__(256) void prep_gemm(
    const float* __restrict__ h,
    const unsigned short* __restrict__ W1e1, const unsigned short* __restrict__ W1e2,
    const unsigned short* __restrict__ W1c1, const unsigned short* __restrict__ W1c2,
    const float* __restrict__ e1b, const float* __restrict__ c1b,
    float* __restrict__ A1e, float* __restrict__ A2e,
    float* __restrict__ A1c, float* __restrict__ A2c) {
    const int tid = threadIdx.x;
    const int lane = tid & 63, wv = tid >> 6;   // 4 waves
    const int c = lane & 15, q = lane >> 4;
    const int r0 = blockIdx.x * 16;

    const unsigned short* Wt = (wv == 0) ? W1e1 : (wv == 1) ? W1e2 : (wv == 2) ? W1c1 : W1c2;
    float* O = (wv == 0) ? A1e : (wv == 1) ? A2e : (wv == 2) ? A1c : A2c;
    const float* bias = (wv == 0) ? e1b : (wv == 2) ? c1b : (const float*)0;

    f32x4 acc[8];
    const f32x4 zf = {0.f, 0.f, 0.f, 0.f};
#pragma unroll
    for (int nt = 0; nt < 8; ++nt) acc[nt] = zf;

    const float* hrow = h + (size_t)(r0 + c) * HD;
#pragma unroll
    for (int ks = 0; ks < 4; ++ks) {
        const int kb = ks * 32 + q * 8;
        float4 hlo = *(const float4*)(hrow + kb);
        float4 hhi = *(const float4*)(hrow + kb + 4);
        short8 af;
        af[0] = (short)f2bf(hlo.x); af[1] = (short)f2bf(hlo.y);
        af[2] = (short)f2bf(hlo.z); af[3] = (short)f2bf(hlo.w);
        af[4] = (short)f2bf(hhi.x); af[5] = (short)f2bf(hhi.y);
        af[6] = (short)f2bf(hhi.z); af[7] = (short)f2bf(hhi.w);
#pragma unroll
        for (int nt = 0; nt < 8; ++nt) {
            short8 Bf = *(const short8*)(Wt + (nt * 16 + c) * HD + kb);
            acc[nt] = __builtin_amdgcn_mfma_f32_16x16x32_bf16(af, Bf, acc[nt], 0, 0, 0);
        }
    }
#pragma unroll
    for (int nt = 0; nt < 8; ++nt) {
        float bb = bias ? bias[nt * 16 + c] : 0.f;
#pragma unroll
        for (int reg = 0; reg < 4; ++reg)
            O[(size_t)(r0 + q * 4 + reg) * HD + nt * 16 + c] = acc[nt][reg] + bb;
    }
}

// ---------------------------------------------------------------------------
// Main fused kernel: one workgroup (1024 thr, 16 waves) per (b,i).
// Single shared weight LDS buffer (staged twice) -> ~59 KB LDS -> 2 blocks/CU.
// ---------------------------------------------------------------------------
__global__ __launch_bounds__(1024, 8) void egc_main(
    const float* __restrict__ x, const float* __restrict__ h,
    const float* __restrict__ x0, const float* __restrict__ pmask,
    const float* __restrict__ e1w,
    const float* __restrict__ e2b, const float* __restrict__ eiw,
    const float* __restrict__ eib,
    const float* __restrict__ n1w, const float* __restrict__ n1b,
    const float* __restrict__ n2w, const float* __restrict__ n2b,
    const float* __restrict__ c1w, const float* __restrict__ c2b,
    const float* __restrict__ c3w, const float* __restrict__ c3b,
    const float* __restrict__ A1e, const float* __restrict__ A2e,
    const float* __restrict__ A1c, const float* __restrict__ A2c,
    const unsigned short* __restrict__ WtE, const unsigned short* __restrict__ WtC,
    float* __restrict__ xout, float* __restrict__ hout) {

    __shared__ __align__(16) unsigned short Wl[HD * WSTRIDE];    // 34.8 KB (shared E/C)
    __shared__ __align__(16) float xs[BN][4];
    __shared__ __align__(16) float x0s[BN][4];
    __shared__ __align__(16) float d2s[BN], d02s[BN], rsh[BN];
    __shared__ __align__(16) float vE0[HD], vE1[HD], vE2[HD];
    __shared__ __align__(16) float vC0[HD], vC1[HD], vC2[HD];
    __shared__ __align__(16) float hsv[HD];
    __shared__ __align__(16) float aggbuf[16][HD];   // also reused by node MLP
    __shared__ __align__(16) float aggv[HD];
    __shared__ float updbuf[16][4];
    __shared__ float smask;

    const int tid = threadIdx.x;
    const int bi  = blockIdx.x;         // 0..2047
    const int b   = bi >> 8;
    const int i   = bi & 255;
    const int row = bi;

    // ---- stage edge weights into LDS (padded rows) ----
#pragma unroll
    for (int u = 0; u < 2; ++u) {
        int idx = u * 1024 + tid;        // 0..2047 chunks of 8 bf16
        int n   = idx >> 4;
        int k8  = (idx & 15) * 8;
        *(ushort8_t*)(Wl + n * WSTRIDE + k8) = *(const ushort8_t*)(WtE + n * HD + k8);
    }

    // ---- setup loads ----
    if (tid < BN) {
        int gj = b * BN + tid;
        xs[tid][0]  = x[gj * 3 + 0];
        xs[tid][1]  = x[gj * 3 + 1];
        xs[tid][2]  = x[gj * 3 + 2];
        x0s[tid][0] = x0[gj * 3 + 0];
        x0s[tid][1] = x0[gj * 3 + 1];
        x0s[tid][2] = x0[gj * 3 + 2];
    } else if (tid < BN + HD) {
        int t = tid - BN;
        vE0[t] = A1e[row * HD + t];
        vE1[t] = e1w[256 * HD + t];
        vE2[t] = e1w[257 * HD + t];
    } else if (tid < BN + 2 * HD) {
        int t = tid - BN - HD;
        vC0[t] = A1c[row * HD + t];
        vC1[t] = c1w[256 * HD + t];
        vC2[t] = c1w[257 * HD + t];
    } else if (tid < BN + 3 * HD) {
        int t = tid - BN - 2 * HD;
        hsv[t] = h[row * HD + t];
    }
    if (tid == 1023) smask = pmask[row];
    __syncthreads();

    // ---- pairwise distances vs row i ----
    if (tid < BN) {
        float dx = xs[i][0] - xs[tid][0];
        float dy = xs[i][1] - xs[tid][1];
        float dz = xs[i][2] - xs[tid][2];
        float d2 = dx * dx + dy * dy + dz * dz;
        d2s[tid] = d2;
        float dist = (d2 > 0.0f) ? sqrtf(d2) : 0.0f;
        rsh[tid] = __builtin_amdgcn_rcpf(dist + 1.0f);
        float ex = x0s[i][0] - x0s[tid][0];
        float ey = x0s[i][1] - x0s[tid][1];
        float ez = x0s[i][2] - x0s[tid][2];
        d02s[tid] = ex * ex + ey * ey + ez * ez;
    }
    __syncthreads();

    const int lane = tid & 63, wv = tid >> 6;   // 16 waves
    const int c = lane & 15, q = lane >> 4;
    const int ra = wv * 16 + c;                 // A-fragment row

    // =================== EDGE PATH ===================
    {
        const float* A2g = A2e + (size_t)b * BN * HD;
        f32x4 acc[8];
        const f32x4 zf = {0.f, 0.f, 0.f, 0.f};
#pragma unroll
        for (int nt = 0; nt < 8; ++nt) acc[nt] = zf;
        const float d2v = d2s[ra], d02v = d02s[ra];
#pragma unroll
        for (int ks = 0; ks < 4; ++ks) {
            const int kb = ks * 32 + q * 8;
            float4 alo = *(const float4*)(A2g + ra * HD + kb);
            float4 ahi = *(const float4*)(A2g + ra * HD + kb + 4);
            float4 p0 = *(const float4*)(vE0 + kb);
            float4 p0h = *(const float4*)(vE0 + kb + 4);
            float4 p1 = *(const float4*)(vE1 + kb);
            float4 p1h = *(const float4*)(vE1 + kb + 4);
            float4 p2 = *(const float4*)(vE2 + kb);
            float4 p2h = *(const float4*)(vE2 + kb + 4);
            short8 af;
            af[0] = (short)f2bf(fsilu(alo.x + p0.x + d2v * p1.x + d02v * p2.x));
            af[1] = (short)f2bf(fsilu(alo.y + p0.y + d2v * p1.y + d02v * p2.y));
            af[2] = (short)f2bf(fsilu(alo.z + p0.z + d2v * p1.z + d02v * p2.z));
            af[3] = (short)f2bf(fsilu(alo.w + p0.w + d2v * p1.w + d02v * p2.w));
            af[4] = (short)f2bf(fsilu(ahi.x + p0h.x + d2v * p1h.x + d02v * p2h.x));
            af[5] = (short)f2bf(fsilu(ahi.y + p0h.y + d2v * p1h.y + d02v * p2h.y));
            af[6] = (short)f2bf(fsilu(ahi.z + p0h.z + d2v * p1h.z + d02v * p2h.z));
            af[7] = (short)f2bf(fsilu(ahi.w + p0h.w + d2v * p1h.w + d02v * p2h.w));
#pragma unroll
            for (int nt = 0; nt < 8; ++nt) {
                short8 Bf = *(const short8*)(Wl + (nt * 16 + c) * WSTRIDE + kb);
                acc[nt] = __builtin_amdgcn_mfma_f32_16x16x32_bf16(af, Bf, acc[nt], 0, 0, 0);
            }
        }
        // epilogue: gate + aggregate
        float b2l[8], wIl[8];
#pragma unroll
        for (int nt = 0; nt < 8; ++nt) {
            b2l[nt] = e2b[nt * 16 + c];
            wIl[nt] = eiw[nt * 16 + c];
        }
        float bI = eib[0];
        float aggp[8] = {0,0,0,0,0,0,0,0};
#pragma unroll
        for (int reg = 0; reg < 4; ++reg) {
            int r = wv * 16 + q * 4 + reg;
            float mv[8]; float ed = 0.f;
#pragma unroll
            for (int nt = 0; nt < 8; ++nt) {
                mv[nt] = fsilu(acc[nt][reg] + b2l[nt]);
                ed += mv[nt] * wIl[nt];
            }
            ed += __shfl_xor(ed, 1);
            ed += __shfl_xor(ed, 2);
            ed += __shfl_xor(ed, 4);
            ed += __shfl_xor(ed, 8);
            float e = (r == i) ? 0.0f : fsigmoid(ed + bI);
#pragma unroll
            for (int nt = 0; nt < 8; ++nt) aggp[nt] += e * mv[nt];
        }
#pragma unroll
        for (int nt = 0; nt < 8; ++nt) {
            aggp[nt] += __shfl_xor(aggp[nt], 16);
            aggp[nt] += __shfl_xor(aggp[nt], 32);
        }
        if (q == 0)
#pragma unroll
            for (int nt = 0; nt < 8; ++nt) aggbuf[wv][nt * 16 + c] = aggp[nt];
    }
    __syncthreads();

    // ---- agg reduction + restage coord weights (overlapped) ----
    if (tid < HD) {
        float s = 0.f;
#pragma unroll
        for (int w = 0; w < 16; ++w) s += aggbuf[w][tid];
        aggv[tid] = s * (1.0f / 256.0f);
    }
#pragma unroll
    for (int u = 0; u < 2; ++u) {
        int idx = u * 1024 + tid;
        int n   = idx >> 4;
        int k8  = (idx & 15) * 8;
        *(ushort8_t*)(Wl + n * WSTRIDE + k8) = *(const ushort8_t*)(WtC + n * HD + k8);
    }
    __syncthreads();

    // =================== COORD PATH ===================
    {
        const float* A2g = A2c + (size_t)b * BN * HD;
        f32x4 acc[8];
        const f32x4 zf = {0.f, 0.f, 0.f, 0.f};
#pragma unroll
        for (int nt = 0; nt < 8; ++nt) acc[nt] = zf;
        const float d2v = d2s[ra], d02v = d02s[ra];
#pragma unroll
        for (int ks = 0; ks < 4; ++ks) {
            const int kb = ks * 32 + q * 8;
            float4 alo = *(const float4*)(A2g + ra * HD + kb);
            float4 ahi = *(const float4*)(A2g + ra * HD + kb + 4);
            float4 p0 = *(const float4*)(vC0 + kb);
            float4 p0h = *(const float4*)(vC0 + kb + 4);
            float4 p1 = *(const float4*)(vC1 + kb);
            float4 p1h = *(const float4*)(vC1 + kb + 4);
            float4 p2 = *(const float4*)(vC2 + kb);
            float4 p2h = *(const float4*)(vC2 + kb + 4);
            short8 af;
            af[0] = (short)f2bf(fsilu(alo.x + p0.x + d2v * p1.x + d02v * p2.x));
            af[1] = (short)f2bf(fsilu(alo.y + p0.y + d2v * p1.y + d02v * p2.y));
            af[2] = (short)f2bf(fsilu(alo.z + p0.z + d2v * p1.z + d02v * p2.z));
            af[3] = (short)f2bf(fsilu(alo.w + p0.w + d2v * p1.w + d02v * p2.w));
            af[4] = (short)f2bf(fsilu(ahi.x + p0h.x + d2v * p1h.x + d02v * p2h.x));
            af[5] = (short)f2bf(fsilu(ahi.y + p0h.y + d2v * p1h.y + d02v * p2h.y));
            af[6] = (short)f2bf(fsilu(ahi.z + p0h.z + d2v * p1h.z + d02v * p2h.z));
            af[7] = (short)f2bf(fsilu(ahi.w + p0h.w + d2v * p1h.w + d02v * p2h.w));
#pragma unroll
            for (int nt = 0; nt < 8; ++nt) {
                short8 Bf = *(const short8*)(Wl + (nt * 16 + c) * WSTRIDE + kb);
                acc[nt] = __builtin_amdgcn_mfma_f32_16x16x32_bf16(af, Bf, acc[nt], 0, 0, 0);
            }
        }
        float b2l[8], w3l[8];
#pragma unroll
        for (int nt = 0; nt < 8; ++nt) {
            b2l[nt] = c2b[nt * 16 + c];
            w3l[nt] = c3w[nt * 16 + c];
        }
        float b3 = c3b[0];
        float updp = 0.f;
        float xic = (c < 3) ? xs[i][c] : 0.f;
#pragma unroll
        for (int reg = 0; reg < 4; ++reg) {
            int r = wv * 16 + q * 4 + reg;
            float cd = 0.f;
#pragma unroll
            for (int nt = 0; nt < 8; ++nt)
                cd += fsilu(acc[nt][reg] + b2l[nt]) * w3l[nt];
            cd += __shfl_xor(cd, 1);
            cd += __shfl_xor(cd, 2);
            cd += __shfl_xor(cd, 4);
            cd += __shfl_xor(cd, 8);
            float cw = cd + b3;
            if (c < 3 && r != i)
                updp += cw * (xic - xs[r][c]) * rsh[r];
        }
        updp += __shfl_xor(updp, 16);
        updp += __shfl_xor(updp, 32);
        if (q == 0 && c < 3) updbuf[wv][c] = updp;
    }
    __syncthreads();

    // x output (float32)
    if (tid < 3) {
        float u = 0.f;
#pragma unroll
        for (int w = 0; w < 16; ++w) u += updbuf[w][tid];
        u *= (1.0f / 256.0f);
        xout[row * 3 + tid] = (xs[i][tid] + u) * smask;
    }

    // =================== NODE MLP ===================
    // h_next = (h + silu([h,agg]@W1 + b1)@W2 + b2) * mask
    float* npart = &aggbuf[0][0];           // rows 0..7
    float* qv    = &aggbuf[8][0];           // row 8
    {
        int k = tid & 127, part = tid >> 7;        // 0..7, 32 features each
        const float* src = (part < 4) ? hsv : aggv;
        int fbase = (part & 3) * 32;
        int wrow = ((part < 4) ? 0 : HD) + fbase;
        float s = 0.f;
#pragma unroll 4
        for (int f = 0; f < 32; ++f)
            s += src[fbase + f] * n1w[(size_t)(wrow + f) * HD + k];
        npart[part * HD + k] = s;
    }
    __syncthreads();
    if (tid < HD) {
        float s = n1b[tid];
#pragma unroll
        for (int p = 0; p < 8; ++p) s += npart[p * HD + tid];
        qv[tid] = fsilu(s);
    }
    __syncthreads();
    {
        int o = tid & 127, p = tid >> 7;           // 16 features each
        float s = 0.f;
#pragma unroll 4
        for (int f = 0; f < 16; ++f) {
            int ff = p * 16 + f;
            s += qv[ff] * n2w[(size_t)ff * HD + o];
        }
        npart[p * HD + o] = s;                      // overwrite rows 0..7 (consumed)
    }
    __syncthreads();
    if (tid < HD) {
        float s = 0.f;
#pragma unroll
        for (int p = 0; p < 8; ++p) s += npart[p * HD + tid];
        hout[(size_t)row * HD + tid] = (hsv[tid] + s + n2b[tid]) * smask;
    }
}

extern "C" void kernel_launch(void* const* d_in, const int* in_sizes, int n_in,
                              void* d_out, int out_size, void* d_ws, size_t ws_size,
                              hipStream_t stream) {
    const float* x    = (const float*)d_in[0];
    const float* h    = (const float*)d_in[1];
    const float* x0   = (const float*)d_in[2];
    const float* pm   = (const float*)d_in[3];
    const float* e1w  = (const float*)d_in[4];
    const float* e1b  = (const float*)d_in[5];
    const float* e2w  = (const float*)d_in[6];
    const float* e2b  = (const float*)d_in[7];
    const float* eiw  = (const float*)d_in[8];
    const float* eib  = (const float*)d_in[9];
    const float* n1w  = (const float*)d_in[10];
    const float* n1b  = (const float*)d_in[11];
    const float* n2w  = (const float*)d_in[12];
    const float* n2b  = (const float*)d_in[13];
    const float* c1w  = (const float*)d_in[14];
    const float* c1b  = (const float*)d_in[15];
    const float* c2w  = (const float*)d_in[16];
    const float* c2b  = (const float*)d_in[17];
    const float* c3w  = (const float*)d_in[18];
    const float* c3b  = (const float*)d_in[19];

    float* wsf = (float*)d_ws;
    const size_t nA = 2048 * 128;
    float* A1e = wsf;
    float* A2e = wsf + nA;
    float* A1c = wsf + 2 * nA;
    float* A2c = wsf + 3 * nA;
    unsigned short* WtE  = (unsigned short*)(wsf + 4 * nA);
    unsigned short* WtC  = WtE  + 128 * 128;
    unsigned short* W1e1 = WtC  + 128 * 128;
    unsigned short* W1e2 = W1e1 + 128 * 128;
    unsigned short* W1c1 = W1e2 + 128 * 128;
    unsigned short* W1c2 = W1c1 + 128 * 128;

    float* xout = (float*)d_out;
    float* hout = xout + 8 * 256 * 3;

    prep_tw<<<dim3(128), dim3(256), 0, stream>>>(e2w, c2w, e1w, c1w,
                                                 WtE, WtC, W1e1, W1e2, W1c1, W1c2);
    prep_gemm<<<dim3(128), dim3(256), 0, stream>>>(h, W1e1, W1e2, W1c1, W1c2,
                                                   e1b, c1b, A1e, A2e, A1c, A2c);
    egc_main<<<dim3(2048), dim3(1024), 0, stream>>>(
        x, h, x0, pm, e1w, e2b, eiw, eib, n1w, n1b, n2w, n2b,
        c1w, c2b, c3w, c3b, A1e, A2e, A1c, A2c, WtE, WtC, xout, hout);
}